// Round 9
// baseline (783.956 us; speedup 1.0000x reference)
//
#include <hip/hip_runtime.h>

typedef _Float16 half8 __attribute__((ext_vector_type(8)));
typedef _Float16 half4 __attribute__((ext_vector_type(4)));
typedef float f32x4 __attribute__((ext_vector_type(4)));

// ---------------------------------------------------------------- transpose
__global__ __launch_bounds__(256) void transpose_f32(
    const float* __restrict__ in, int lda,
    float* __restrict__ out, int ldo)
{
  __shared__ float t[32][33];
  const int tx = threadIdx.x & 31, ty = threadIdx.x >> 5;
  const int bc = blockIdx.x * 32, br = blockIdx.y * 32;
#pragma unroll
  for (int i = 0; i < 4; ++i)
    t[ty + 8 * i][tx] = in[(size_t)(br + ty + 8 * i) * lda + bc + tx];
  __syncthreads();
#pragma unroll
  for (int i = 0; i < 4; ++i)
    out[(size_t)(bc + ty + 8 * i) * ldo + br + tx] = t[tx][ty + 8 * i];
}

// transpose with f32 -> f16 convert on output
__global__ __launch_bounds__(256) void transpose_f32_f16(
    const float* __restrict__ in, int lda,
    _Float16* __restrict__ out, int ldo)
{
  __shared__ float t[32][33];
  const int tx = threadIdx.x & 31, ty = threadIdx.x >> 5;
  const int bc = blockIdx.x * 32, br = blockIdx.y * 32;
#pragma unroll
  for (int i = 0; i < 4; ++i)
    t[ty + 8 * i][tx] = in[(size_t)(br + ty + 8 * i) * lda + bc + tx];
  __syncthreads();
#pragma unroll
  for (int i = 0; i < 4; ++i)
    out[(size_t)(bc + ty + 8 * i) * ldo + br + tx] = (_Float16)t[tx][ty + 8 * i];
}

// ---------------------------------------------------------------- half column-sum
__global__ __launch_bounds__(256) void halfcolsum(
    const float* __restrict__ k0T, float* __restrict__ csum)
{
  const int d = blockIdx.x, tid = threadIdx.x;
  const float4* p = (const float4*)(k0T + (size_t)d * 8192);
  float s = 0.f;
#pragma unroll
  for (int i = 0; i < 8; ++i) {
    float4 v = p[i * 256 + tid];
    s += (v.x + v.y) + (v.z + v.w);
  }
#pragma unroll
  for (int off = 32; off; off >>= 1) s += __shfl_xor(s, off);
  __shared__ float r[4];
  if ((tid & 63) == 0) r[tid >> 6] = s;
  __syncthreads();
  if (tid == 0) csum[d] = 0.5f * ((r[0] + r[1]) + (r[2] + r[3]));
}

// ---------------------------------------------------------------- GEMM (BT), f32 in
template<int ASPL,int BSPL,int BM,int BN,int WAVES_M,int WAVES_N,int THREADS,
         int APART,bool KSPLIT,bool QF16,int MINW>
__global__ __launch_bounds__(THREADS, MINW) void gemm_bt(
    const float* __restrict__ Ag, int lda, size_t a_plane,
    const float* __restrict__ Bg, int ldb,
    float* __restrict__ Cg, int ldc, size_t c_plane,
    const float* __restrict__ bias, int K, float scale,
    _Float16* __restrict__ q16out)
{
  constexpr int BK = 32;
  constexpr int WM = BM / WAVES_M, WN = BN / WAVES_N;
  constexpr int FM = WM / 16, FN = WN / 16;
  constexpr int NCA = (BM * 4) / THREADS;
  constexpr int NCB = (BN * 4) / THREADS;
  static_assert((BM * 4) % THREADS == 0 && (BN * 4) % THREADS == 0, "mismatch");

  __shared__ _Float16 ldsA[2][ASPL][BM][BK];
  __shared__ _Float16 ldsB[2][BSPL][BN][BK];

  const int tid  = threadIdx.x;
  const int lane = tid & 63;
  const int wid  = tid >> 6;
  const int wrow = wid / WAVES_N, wcol = wid % WAVES_N;
  const int l15  = lane & 15, g = lane >> 4;
  const int brow = blockIdx.y * BM;
  const int bcol = blockIdx.x * BN;

  if constexpr (KSPLIT) {
    const int kc = blockIdx.z;
    Ag += (size_t)kc * K;
    Bg += (size_t)kc * K;
    Cg += (size_t)kc * c_plane;
  }

  f32x4 acc[FM][FN];
#pragma unroll
  for (int mi = 0; mi < FM; ++mi)
#pragma unroll
    for (int ni = 0; ni < FN; ++ni)
      acc[mi][ni] = (f32x4){0.f, 0.f, 0.f, 0.f};

  float4 ra[NCA][2], rb[NCB][2];

  auto loadAB = [&](int kt) {
    const int k0 = kt * BK;
#pragma unroll
    for (int i = 0; i < NCA; ++i) {
      int c = tid + THREADS * i;
      int row = c >> 2, ci = c & 3;
      const float* bp = Ag + (size_t)(brow + row) * lda + k0 + ci * 8;
      float4 u0 = ((const float4*)bp)[0];
      float4 u1 = ((const float4*)bp)[1];
#pragma unroll
      for (int p = 1; p < APART; ++p) {
        const float* pp = bp + (size_t)p * a_plane;
        float4 w0 = ((const float4*)pp)[0], w1 = ((const float4*)pp)[1];
        u0.x += w0.x; u0.y += w0.y; u0.z += w0.z; u0.w += w0.w;
        u1.x += w1.x; u1.y += w1.y; u1.z += w1.z; u1.w += w1.w;
      }
      ra[i][0] = u0; ra[i][1] = u1;
    }
#pragma unroll
    for (int i = 0; i < NCB; ++i) {
      int c = tid + THREADS * i;
      int row = c >> 2, ci = c & 3;
      const float4* p = (const float4*)(Bg + (size_t)(bcol + row) * ldb + k0 + ci * 8);
      rb[i][0] = p[0]; rb[i][1] = p[1];
    }
  };

  auto stageLDS = [&](int b) {
#pragma unroll
    for (int i = 0; i < NCA; ++i) {
      int c = tid + THREADS * i;
      int row = c >> 2, ci = c & 3;
      float f[8] = {ra[i][0].x, ra[i][0].y, ra[i][0].z, ra[i][0].w,
                    ra[i][1].x, ra[i][1].y, ra[i][1].z, ra[i][1].w};
      half8 h, l;
#pragma unroll
      for (int j = 0; j < 8; ++j) {
        _Float16 hv = (_Float16)f[j];
        h[j] = hv;
        if (ASPL == 2) l[j] = (_Float16)(f[j] - (float)hv);
      }
      int off = row * BK + ((ci ^ ((row >> 1) & 3)) << 3);
      *(half8*)(&ldsA[b][0][0][0] + off) = h;
      if (ASPL == 2) *(half8*)(&ldsA[b][1][0][0] + off) = l;
    }
#pragma unroll
    for (int i = 0; i < NCB; ++i) {
      int c = tid + THREADS * i;
      int row = c >> 2, ci = c & 3;
      float f[8] = {rb[i][0].x, rb[i][0].y, rb[i][0].z, rb[i][0].w,
                    rb[i][1].x, rb[i][1].y, rb[i][1].z, rb[i][1].w};
      half8 h, l;
#pragma unroll
      for (int j = 0; j < 8; ++j) {
        _Float16 hv = (_Float16)f[j];
        h[j] = hv;
        if (BSPL == 2) l[j] = (_Float16)(f[j] - (float)hv);
      }
      int off = row * BK + ((ci ^ ((row >> 1) & 3)) << 3);
      *(half8*)(&ldsB[b][0][0][0] + off) = h;
      if (BSPL == 2) *(half8*)(&ldsB[b][1][0][0] + off) = l;
    }
  };

  const int nk = K / BK;
  loadAB(0);
  stageLDS(0);
  if (nk > 1) loadAB(1);
  __syncthreads();

  for (int kt = 0; kt < nk; ++kt) {
    const int cur = kt & 1, nxt = cur ^ 1;
    if (kt + 1 < nk) stageLDS(nxt);
    if (kt + 2 < nk) loadAB(kt + 2);

    half8 af[FM][ASPL];
#pragma unroll
    for (int mi = 0; mi < FM; ++mi)
#pragma unroll
      for (int sa = 0; sa < ASPL; ++sa) {
        int row = wrow * WM + mi * 16 + l15;
        af[mi][sa] = *(const half8*)(&ldsA[cur][sa][0][0] + row * BK + ((g ^ ((row >> 1) & 3)) << 3));
      }
#pragma unroll
    for (int ni = 0; ni < FN; ++ni) {
      half8 bf[BSPL];
#pragma unroll
      for (int sb = 0; sb < BSPL; ++sb) {
        int row = wcol * WN + ni * 16 + l15;
        bf[sb] = *(const half8*)(&ldsB[cur][sb][0][0] + row * BK + ((g ^ ((row >> 1) & 3)) << 3));
      }
#pragma unroll
      for (int mi = 0; mi < FM; ++mi)
#pragma unroll
        for (int sa = 0; sa < ASPL; ++sa)
#pragma unroll
          for (int sb = 0; sb < BSPL; ++sb) {
            if (ASPL == 2 && BSPL == 2 && sa == 1 && sb == 1) continue;
            acc[mi][ni] = __builtin_amdgcn_mfma_f32_16x16x32_f16(af[mi][sa], bf[sb], acc[mi][ni], 0, 0, 0);
          }
    }
    __syncthreads();
  }

#pragma unroll
  for (int mi = 0; mi < FM; ++mi)
#pragma unroll
    for (int ni = 0; ni < FN; ++ni) {
      int col = bcol + wcol * WN + ni * 16 + l15;
      float bv = bias ? bias[col] : 0.f;
#pragma unroll
      for (int j = 0; j < 4; ++j) {
        int r = brow + wrow * WM + mi * 16 + g * 4 + j;
        float v = acc[mi][ni][j] * scale + bv;
        Cg[(size_t)r * ldc + col] = v;
        if constexpr (QF16) {
          if (col < 512) q16out[(size_t)r * 512 + col] = (_Float16)v;
        }
      }
    }
}

// ---------------------------------------------------------------- GEMM f16 x f16 (K3)
template<int BM,int BN,int THREADS,bool STATS,int MINW>
__global__ __launch_bounds__(THREADS, MINW) void gemm_ff16(
    const _Float16* __restrict__ Ag, int lda,
    const _Float16* __restrict__ Bg, int ldb,
    float* __restrict__ Cg, int ldc,
    int K, float scale,
    float* __restrict__ mxout, float* __restrict__ smout, int ntiles)
{
  constexpr int BK = 32;
  constexpr int WAVES_M = 2, WAVES_N = 2;
  constexpr int WM = BM / WAVES_M, WN = BN / WAVES_N;
  constexpr int FM = WM / 16, FN = WN / 16;
  constexpr int NCA = (BM * 4) / THREADS;
  constexpr int NCB = (BN * 4) / THREADS;

  __shared__ _Float16 ldsA[2][BM][BK];
  __shared__ _Float16 ldsB[2][BN][BK];

  const int tid  = threadIdx.x;
  const int lane = tid & 63;
  const int wid  = tid >> 6;
  const int wrow = wid >> 1, wcol = wid & 1;
  const int l15  = lane & 15, g = lane >> 4;
  const int brow = blockIdx.y * BM;
  const int bcol = blockIdx.x * BN;

  f32x4 acc[FM][FN];
#pragma unroll
  for (int mi = 0; mi < FM; ++mi)
#pragma unroll
    for (int ni = 0; ni < FN; ++ni)
      acc[mi][ni] = (f32x4){0.f, 0.f, 0.f, 0.f};

  half8 ra[NCA], rb[NCB];

  auto loadAB = [&](int kt) {
    const int k0 = kt * BK;
#pragma unroll
    for (int i = 0; i < NCA; ++i) {
      int c = tid + THREADS * i;
      int row = c >> 2, ci = c & 3;
      ra[i] = *(const half8*)(Ag + (size_t)(brow + row) * lda + k0 + ci * 8);
    }
#pragma unroll
    for (int i = 0; i < NCB; ++i) {
      int c = tid + THREADS * i;
      int row = c >> 2, ci = c & 3;
      rb[i] = *(const half8*)(Bg + (size_t)(bcol + row) * ldb + k0 + ci * 8);
    }
  };

  auto stageLDS = [&](int b) {
#pragma unroll
    for (int i = 0; i < NCA; ++i) {
      int c = tid + THREADS * i;
      int row = c >> 2, ci = c & 3;
      int off = row * BK + ((ci ^ ((row >> 1) & 3)) << 3);
      *(half8*)(&ldsA[b][0][0] + off) = ra[i];
    }
#pragma unroll
    for (int i = 0; i < NCB; ++i) {
      int c = tid + THREADS * i;
      int row = c >> 2, ci = c & 3;
      int off = row * BK + ((ci ^ ((row >> 1) & 3)) << 3);
      *(half8*)(&ldsB[b][0][0] + off) = rb[i];
    }
  };

  const int nk = K / BK;
  loadAB(0);
  stageLDS(0);
  if (nk > 1) loadAB(1);
  __syncthreads();

  for (int kt = 0; kt < nk; ++kt) {
    const int cur = kt & 1, nxt = cur ^ 1;
    if (kt + 1 < nk) stageLDS(nxt);
    if (kt + 2 < nk) loadAB(kt + 2);

    half8 af[FM];
#pragma unroll
    for (int mi = 0; mi < FM; ++mi) {
      int row = wrow * WM + mi * 16 + l15;
      af[mi] = *(const half8*)(&ldsA[cur][0][0] + row * BK + ((g ^ ((row >> 1) & 3)) << 3));
    }
#pragma unroll
    for (int ni = 0; ni < FN; ++ni) {
      int row = wcol * WN + ni * 16 + l15;
      half8 bf = *(const half8*)(&ldsB[cur][0][0] + row * BK + ((g ^ ((row >> 1) & 3)) << 3));
#pragma unroll
      for (int mi = 0; mi < FM; ++mi)
        acc[mi][ni] = __builtin_amdgcn_mfma_f32_16x16x32_f16(af[mi], bf, acc[mi][ni], 0, 0, 0);
    }
    __syncthreads();
  }

#pragma unroll
  for (int mi = 0; mi < FM; ++mi)
#pragma unroll
    for (int ni = 0; ni < FN; ++ni) {
      int col = bcol + wcol * WN + ni * 16 + l15;
#pragma unroll
      for (int j = 0; j < 4; ++j) {
        int r = brow + wrow * WM + mi * 16 + g * 4 + j;
        Cg[(size_t)r * ldc + col] = acc[mi][ni][j] * scale;
      }
    }

  if constexpr (STATS) {
    __shared__ float s_m2[BM][2];
    __shared__ float s_s2[BM][2];
#pragma unroll
    for (int mi = 0; mi < FM; ++mi)
#pragma unroll
      for (int j = 0; j < 4; ++j) {
        float v = -3.4e38f;
#pragma unroll
        for (int ni = 0; ni < FN; ++ni) v = fmaxf(v, acc[mi][ni][j] * scale);
        v = fmaxf(v, __shfl_xor(v, 1)); v = fmaxf(v, __shfl_xor(v, 2));
        v = fmaxf(v, __shfl_xor(v, 4)); v = fmaxf(v, __shfl_xor(v, 8));
        if (l15 == 0) s_m2[wrow * WM + mi * 16 + g * 4 + j][wcol] = v;
      }
    __syncthreads();
#pragma unroll
    for (int mi = 0; mi < FM; ++mi)
#pragma unroll
      for (int j = 0; j < 4; ++j) {
        int r = wrow * WM + mi * 16 + g * 4 + j;
        float mt = fmaxf(s_m2[r][0], s_m2[r][1]);
        float s = 0.f;
#pragma unroll
        for (int ni = 0; ni < FN; ++ni) s += __expf(acc[mi][ni][j] * scale - mt);
        s += __shfl_xor(s, 1); s += __shfl_xor(s, 2);
        s += __shfl_xor(s, 4); s += __shfl_xor(s, 8);
        if (l15 == 0) s_s2[r][wcol] = s;
      }
    __syncthreads();
    if (tid < BM) {
      float mt = fmaxf(s_m2[tid][0], s_m2[tid][1]);
      float st = s_s2[tid][0] + s_s2[tid][1];
      mxout[(size_t)(brow + tid) * ntiles + blockIdx.x] = mt;
      smout[(size_t)(brow + tid) * ntiles + blockIdx.x] = st;
    }
  }
}

// ---------------------------------------------------------------- reduce 4 planes -> f16
__global__ __launch_bounds__(256) void reduce4_f16(
    const float4* __restrict__ in, _Float16* __restrict__ out16, size_t plane4,
    const float4* __restrict__ csum4)
{
  size_t i = (size_t)blockIdx.x * 256 + threadIdx.x;
  float4 a = in[i], b = in[plane4 + i], c = in[2 * plane4 + i], d = in[3 * plane4 + i];
  float4 s = csum4[i & 127];
  half4 h;
  h[0] = (_Float16)(a.x + b.x + c.x + d.x - s.x);
  h[1] = (_Float16)(a.y + b.y + c.y + d.y - s.y);
  h[2] = (_Float16)(a.z + b.z + c.z + d.z - s.z);
  h[3] = (_Float16)(a.w + b.w + c.w + d.w - s.w);
  *(half4*)(out16 + i * 4) = h;
}

// ---------------------------------------------------------------- stats combine
__global__ __launch_bounds__(256) void softmax_combine(
    const float* __restrict__ mx, const float* __restrict__ sm,
    float* __restrict__ rowm, float* __restrict__ rowinv)
{
  const int row = blockIdx.x * 4 + (threadIdx.x >> 6);
  const int lane = threadIdx.x & 63;
  float mt = mx[(size_t)row * 64 + lane];
  float m = mt;
#pragma unroll
  for (int off = 32; off; off >>= 1) m = fmaxf(m, __shfl_xor(m, off));
  float s = sm[(size_t)row * 64 + lane] * __expf(mt - m);
#pragma unroll
  for (int off = 32; off; off >>= 1) s += __shfl_xor(s, off);
  if (lane == 0) { rowm[row] = m; rowinv[row] = 1.0f / s; }
}

// ---------------------------------------------------------------- fused attn-write + PV
// grid (4 kc, 256 rowblocks) = 1024 blocks, 512 thr.
// BM=32; wave wid owns cols wid*64..+63 (1x8 layout). NO ldsB: V fragments
// loaded directly to registers with ONE-STEP prefetch (latency off the MFMA
// chain; V-chunk 2MB is L2-resident). ldsA tiny (4KB dbuf). A-staging access
// pattern identical to round-5 (tid<256, 32B loads -> 16B exp-stores x2).
__global__ __launch_bounds__(512, 4) void pv_fused(
    float* __restrict__ attn,            // [8192][8192] logits in, attention out
    const _Float16* __restrict__ vT16,   // [512][8192] f16
    const float* __restrict__ rowm, const float* __restrict__ rowinv,
    float* __restrict__ vals_p)          // [4][8192][512]
{
  constexpr int BM = 32, BK = 32, NSTEP = 64;  // KC = 2048
  __shared__ _Float16 ldsA[2][BM][BK];   // 4 KB
  __shared__ float s_m[BM], s_inv[BM];

  const int tid = threadIdx.x, lane = tid & 63, wid = tid >> 6;
  const int l15 = lane & 15, g = lane >> 4;
  const int kc = blockIdx.x, brow = blockIdx.y * BM;
  const size_t kbase = (size_t)kc * 2048;

  if (tid < BM) { s_m[tid] = rowm[brow + tid]; s_inv[tid] = rowinv[brow + tid]; }

  f32x4 acc[2][4];
#pragma unroll
  for (int mi = 0; mi < 2; ++mi)
#pragma unroll
    for (int ni = 0; ni < 4; ++ni) acc[mi][ni] = (f32x4){0.f, 0.f, 0.f, 0.f};

  // A: threads 0..255 stage 32 rows x 32 k, 8 f32 (32B) each — round-5 pattern
  const int arow = (tid & 255) >> 3, aci = tid & 7;   // aci in [0,8): 4-f32 chunks
  // 2 chunks per thread: aci and aci (single float4? no—8 chunks x 32 rows = 256)
  // each thread: ONE float4 (16B)? 32x32 f32 = 1024 = 256 thr x 4 f32. 16B/thread.
  float4 raA, raB;
  half8 bfA[4], bfB[4];

  // B fragment base: wave wid covers cols wid*64..+63
  const _Float16* bbase = vT16 + (size_t)(wid * 64 + l15) * 8192 + kbase + g * 8;

  auto loadA = [&](int kt, float4& ra) {
    if (tid < 256)
      ra = *(const float4*)(attn + (size_t)(brow + arow) * 8192 + kbase + kt * BK + aci * 4);
  };
  auto loadBf = [&](int kt, half8* bf) {
#pragma unroll
    for (int ni = 0; ni < 4; ++ni)
      bf[ni] = *(const half8*)(bbase + (size_t)(ni * 16) * 8192 + kt * BK);
  };
  auto stage = [&](int kt, int b, const float4& ra) {
    if (tid < 256) {
      const float m = s_m[arow], inv = s_inv[arow];
      float e0 = __expf(ra.x - m) * inv;
      float e1 = __expf(ra.y - m) * inv;
      float e2 = __expf(ra.z - m) * inv;
      float e3 = __expf(ra.w - m) * inv;
      *(float4*)(attn + (size_t)(brow + arow) * 8192 + kbase + kt * BK + aci * 4) =
          make_float4(e0, e1, e2, e3);
      half4 h; h[0] = (_Float16)e0; h[1] = (_Float16)e1; h[2] = (_Float16)e2; h[3] = (_Float16)e3;
      int off = arow * BK + (((aci >> 1) ^ ((arow >> 1) & 3)) << 3) + ((aci & 1) << 2);
      *(half4*)(&ldsA[b][0][0] + off) = h;
    }
  };
  auto mfma_step = [&](int b, const half8* bf) {
    half8 af[2];
#pragma unroll
    for (int mi = 0; mi < 2; ++mi) {
      int row = mi * 16 + l15;
      af[mi] = *(const half8*)(&ldsA[b][0][0] + row * BK + ((g ^ ((row >> 1) & 3)) << 3));
    }
    __builtin_amdgcn_s_setprio(1);
#pragma unroll
    for (int ni = 0; ni < 4; ++ni)
#pragma unroll
      for (int mi = 0; mi < 2; ++mi)
        acc[mi][ni] = __builtin_amdgcn_mfma_f32_16x16x32_f16(af[mi], bf[ni], acc[mi][ni], 0, 0, 0);
    __builtin_amdgcn_s_setprio(0);
  };

  loadBf(0, bfA);
  loadA(0, raA);
  __syncthreads();             // s_m / s_inv visible
  stage(0, 0, raA);
  loadA(1, raB);
  __syncthreads();             // buf0 staged

  for (int kt = 0; kt < NSTEP; kt += 2) {
    // even half-step: compute buf0 with bfA
    if (kt + 1 < NSTEP) { loadBf(kt + 1, bfB); stage(kt + 1, 1, raB); }
    if (kt + 2 < NSTEP) loadA(kt + 2, raA);
    mfma_step(0, bfA);
    __syncthreads();
    // odd half-step: compute buf1 with bfB
    if (kt + 2 < NSTEP) { loadBf(kt + 2, bfA); stage(kt + 2, 0, raA); }
    if (kt + 3 < NSTEP) loadA(kt + 3, raB);
    mfma_step(1, bfB);
    __syncthreads();
  }

  const size_t plane = (size_t)8192 * 512;
#pragma unroll
  for (int mi = 0; mi < 2; ++mi)
#pragma unroll
    for (int ni = 0; ni < 4; ++ni) {
      int col = wid * 64 + ni * 16 + l15;
#pragma unroll
      for (int j = 0; j < 4; ++j) {
        int row = brow + mi * 16 + g * 4 + j;
        vals_p[(size_t)kc * plane + (size_t)row * 512 + col] = acc[mi][ni][j];
      }
    }
}

// ---------------------------------------------------------------- launch
extern "C" void kernel_launch(void* const* d_in, const int* in_sizes, int n_in,
                              void* d_out, int out_size, void* d_ws, size_t ws_size,
                              hipStream_t stream)
{
  const float* x    = (const float*)d_in[0];
  const float* Amat = (const float*)d_in[1];
  const float* Wqkv = (const float*)d_in[2];
  const float* bqkv = (const float*)d_in[3];
  const float* Wo   = (const float*)d_in[4];
  const float* bo   = (const float*)d_in[5];

  float* o    = (float*)d_out;                       // [8192,512]
  float* attn = (float*)d_out + (size_t)8192 * 512;  // [8192,8192]

  float* ws = (float*)d_ws;
  float*     vals_p = ws;                         // 16,777,216 floats (4 planes)
  float*     qkv    = ws;                         // 12,582,912 (dead after k0T/vT/q16)
  float*     k0T    = ws + 12582912;              //  4,194,304 (dead after K2/halfcolsum)
  _Float16*  vT16   = (_Float16*)(ws + 16777216); //  2,097,152 float-slots
  float*     WqkvT  = ws + 18874368;              //    786,432
  float*     WoT    = ws + 19660800;              //    262,144
  _Float16*  kbuf16 = (_Float16*)(ws + 19922944); //  2,097,152 float-slots (f16 [8192][512])
  float*     mx     = ws + 24117248;              //    524,288
  float*     sm     = ws + 24641536;              //    524,288
  float*     rowm   = ws + 25165824;              //      8,192
  float*     rowinv = ws + 25174016;              //      8,192
  float*     csum   = ws + 25182208;              //        512 (pad to 1024)
  _Float16*  q16    = (_Float16*)(ws + 25183232); //  2,097,152 float-slots (f16 [8192][512])
  float*     kpart  = attn;                       // d_out attn region pre-K3

  const dim3 b256(256), b512(512);
  const float qk_scale = 0.04419417382415922f;  // 1/sqrt(512)
  const size_t plane = (size_t)8192 * 512;

  transpose_f32<<<dim3(48, 16), b256, 0, stream>>>(Wqkv, 1536, WqkvT, 512);
  transpose_f32<<<dim3(16, 16), b256, 0, stream>>>(Wo, 512, WoT, 512);

  // K1: qkv = x @ Wqkv + bqkv (3-pass) + fused f16 copy of q-third
  gemm_bt<2, 2, 128, 128, 2, 2, 256, 1, false, true, 2>
      <<<dim3(12, 64), b256, 0, stream>>>(
      x, 512, 0, WqkvT, 512, qkv, 1536, 0, bqkv, 512, 1.0f, q16);

  transpose_f32<<<dim3(16, 256), b256, 0, stream>>>(qkv + 512, 1536, k0T, 8192);
  transpose_f32_f16<<<dim3(16, 256), b256, 0, stream>>>(qkv + 1024, 1536, vT16, 8192);
  halfcolsum<<<dim3(512), b256, 0, stream>>>(k0T, csum);

  // K2: k = A @ k0, split-K into 4 chunks, partials in d_out scratch
  gemm_bt<1, 2, 128, 256, 2, 4, 512, 1, true, false, 4>
      <<<dim3(2, 64, 4), b512, 0, stream>>>(
      Amat, 8192, 0, k0T, 8192, kpart, 512, plane, nullptr, 2048, 1.0f, nullptr);

  // kbuf16 = f16(sum of partials - 0.5*colsum(k0))
  reduce4_f16<<<dim3(4096), b256, 0, stream>>>((const float4*)kpart, kbuf16, plane / 4,
                                               (const float4*)csum);

  // K3: logits = (q16 @ kbuf16^T)*scale + per-tile softmax stats
  gemm_ff16<128, 128, 256, true, 4>
      <<<dim3(64, 64), b256, 0, stream>>>(
      q16, 512, kbuf16, 512, attn, 8192, 512, qk_scale, mx, sm, 64);

  softmax_combine<<<dim3(2048), b256, 0, stream>>>(mx, sm, rowm, rowinv);

  // K5': attention = exp(l-m)/s in place; vals partials (B direct-to-reg, prefetched)
  pv_fused<<<dim3(4, 256), b512, 0, stream>>>(attn, vT16, rowm, rowinv, vals_p);

  // K6: o = (sum of 4 vals partials) @ Wo + bo
  gemm_bt<1, 1, 128, 128, 2, 2, 256, 4, false, false, 3>
      <<<dim3(4, 64), b256, 0, stream>>>(
      vals_p, 512, plane, WoT, 512, o, 512, 0, bo, 512, 1.0f, nullptr);
}

// Round 10
// 646.739 us; speedup vs baseline: 1.2122x; 1.2122x over previous
//
#include <hip/hip_runtime.h>

typedef _Float16 half8 __attribute__((ext_vector_type(8)));
typedef _Float16 half4 __attribute__((ext_vector_type(4)));
typedef float f32x4 __attribute__((ext_vector_type(4)));

// ---------------------------------------------------------------- transpose
__global__ __launch_bounds__(256) void transpose_f32(
    const float* __restrict__ in, int lda,
    float* __restrict__ out, int ldo)
{
  __shared__ float t[32][33];
  const int tx = threadIdx.x & 31, ty = threadIdx.x >> 5;
  const int bc = blockIdx.x * 32, br = blockIdx.y * 32;
#pragma unroll
  for (int i = 0; i < 4; ++i)
    t[ty + 8 * i][tx] = in[(size_t)(br + ty + 8 * i) * lda + bc + tx];
  __syncthreads();
#pragma unroll
  for (int i = 0; i < 4; ++i)
    out[(size_t)(bc + ty + 8 * i) * ldo + br + tx] = t[tx][ty + 8 * i];
}

// transpose with f32 -> f16 convert on output
__global__ __launch_bounds__(256) void transpose_f32_f16(
    const float* __restrict__ in, int lda,
    _Float16* __restrict__ out, int ldo)
{
  __shared__ float t[32][33];
  const int tx = threadIdx.x & 31, ty = threadIdx.x >> 5;
  const int bc = blockIdx.x * 32, br = blockIdx.y * 32;
#pragma unroll
  for (int i = 0; i < 4; ++i)
    t[ty + 8 * i][tx] = in[(size_t)(br + ty + 8 * i) * lda + bc + tx];
  __syncthreads();
#pragma unroll
  for (int i = 0; i < 4; ++i)
    out[(size_t)(bc + ty + 8 * i) * ldo + br + tx] = (_Float16)t[tx][ty + 8 * i];
}

// ---------------------------------------------------------------- half column-sum
__global__ __launch_bounds__(256) void halfcolsum(
    const float* __restrict__ k0T, float* __restrict__ csum)
{
  const int d = blockIdx.x, tid = threadIdx.x;
  const float4* p = (const float4*)(k0T + (size_t)d * 8192);
  float s = 0.f;
#pragma unroll
  for (int i = 0; i < 8; ++i) {
    float4 v = p[i * 256 + tid];
    s += (v.x + v.y) + (v.z + v.w);
  }
#pragma unroll
  for (int off = 32; off; off >>= 1) s += __shfl_xor(s, off);
  __shared__ float r[4];
  if ((tid & 63) == 0) r[tid >> 6] = s;
  __syncthreads();
  if (tid == 0) csum[d] = 0.5f * ((r[0] + r[1]) + (r[2] + r[3]));
}

// ---------------------------------------------------------------- GEMM (BT), f32 (or f16 A) in
// AF16==1: A planes are f16 (APART summed in f32 during load).
template<int ASPL,int BSPL,int BM,int BN,int WAVES_M,int WAVES_N,int THREADS,
         int APART,bool KSPLIT,bool QF16,int MINW,int AF16>
__global__ __launch_bounds__(THREADS, MINW) void gemm_bt(
    const void* __restrict__ Agv, int lda, size_t a_plane,
    const float* __restrict__ Bg, int ldb,
    float* __restrict__ Cg, int ldc, size_t c_plane,
    const float* __restrict__ bias, int K, float scale,
    _Float16* __restrict__ q16out)
{
  constexpr int BK = 32;
  constexpr int WM = BM / WAVES_M, WN = BN / WAVES_N;
  constexpr int FM = WM / 16, FN = WN / 16;
  constexpr int NCA = (BM * 4) / THREADS;
  constexpr int NCB = (BN * 4) / THREADS;
  static_assert((BM * 4) % THREADS == 0 && (BN * 4) % THREADS == 0, "mismatch");

  __shared__ _Float16 ldsA[2][ASPL][BM][BK];
  __shared__ _Float16 ldsB[2][BSPL][BN][BK];

  const float* Ag = (const float*)Agv;
  const _Float16* Ag16 = (const _Float16*)Agv;

  const int tid  = threadIdx.x;
  const int lane = tid & 63;
  const int wid  = tid >> 6;
  const int wrow = wid / WAVES_N, wcol = wid % WAVES_N;
  const int l15  = lane & 15, g = lane >> 4;
  const int brow = blockIdx.y * BM;
  const int bcol = blockIdx.x * BN;

  if constexpr (KSPLIT) {
    const int kc = blockIdx.z;
    Ag += (size_t)kc * K;
    Ag16 += (size_t)kc * K;
    Bg += (size_t)kc * K;
    Cg += (size_t)kc * c_plane;
  }

  f32x4 acc[FM][FN];
#pragma unroll
  for (int mi = 0; mi < FM; ++mi)
#pragma unroll
    for (int ni = 0; ni < FN; ++ni)
      acc[mi][ni] = (f32x4){0.f, 0.f, 0.f, 0.f};

  float4 ra[NCA][2], rb[NCB][2];

  auto loadAB = [&](int kt) {
    const int k0 = kt * BK;
#pragma unroll
    for (int i = 0; i < NCA; ++i) {
      int c = tid + THREADS * i;
      int row = c >> 2, ci = c & 3;
      float4 u0, u1;
      if constexpr (AF16 == 1) {
        u0 = make_float4(0.f, 0.f, 0.f, 0.f);
        u1 = make_float4(0.f, 0.f, 0.f, 0.f);
        const _Float16* bp = Ag16 + (size_t)(brow + row) * lda + k0 + ci * 8;
#pragma unroll
        for (int p = 0; p < APART; ++p) {
          half8 hv = *(const half8*)(bp + (size_t)p * a_plane);
          u0.x += (float)hv[0]; u0.y += (float)hv[1]; u0.z += (float)hv[2]; u0.w += (float)hv[3];
          u1.x += (float)hv[4]; u1.y += (float)hv[5]; u1.z += (float)hv[6]; u1.w += (float)hv[7];
        }
      } else {
        const float* bp = Ag + (size_t)(brow + row) * lda + k0 + ci * 8;
        u0 = ((const float4*)bp)[0];
        u1 = ((const float4*)bp)[1];
#pragma unroll
        for (int p = 1; p < APART; ++p) {
          const float* pp = bp + (size_t)p * a_plane;
          float4 w0 = ((const float4*)pp)[0], w1 = ((const float4*)pp)[1];
          u0.x += w0.x; u0.y += w0.y; u0.z += w0.z; u0.w += w0.w;
          u1.x += w1.x; u1.y += w1.y; u1.z += w1.z; u1.w += w1.w;
        }
      }
      ra[i][0] = u0; ra[i][1] = u1;
    }
#pragma unroll
    for (int i = 0; i < NCB; ++i) {
      int c = tid + THREADS * i;
      int row = c >> 2, ci = c & 3;
      const float4* p = (const float4*)(Bg + (size_t)(bcol + row) * ldb + k0 + ci * 8);
      rb[i][0] = p[0]; rb[i][1] = p[1];
    }
  };

  auto stageLDS = [&](int b) {
#pragma unroll
    for (int i = 0; i < NCA; ++i) {
      int c = tid + THREADS * i;
      int row = c >> 2, ci = c & 3;
      float f[8] = {ra[i][0].x, ra[i][0].y, ra[i][0].z, ra[i][0].w,
                    ra[i][1].x, ra[i][1].y, ra[i][1].z, ra[i][1].w};
      half8 h, l;
#pragma unroll
      for (int j = 0; j < 8; ++j) {
        _Float16 hv = (_Float16)f[j];
        h[j] = hv;
        if (ASPL == 2) l[j] = (_Float16)(f[j] - (float)hv);
      }
      int off = row * BK + ((ci ^ ((row >> 1) & 3)) << 3);
      *(half8*)(&ldsA[b][0][0][0] + off) = h;
      if (ASPL == 2) *(half8*)(&ldsA[b][1][0][0] + off) = l;
    }
#pragma unroll
    for (int i = 0; i < NCB; ++i) {
      int c = tid + THREADS * i;
      int row = c >> 2, ci = c & 3;
      float f[8] = {rb[i][0].x, rb[i][0].y, rb[i][0].z, rb[i][0].w,
                    rb[i][1].x, rb[i][1].y, rb[i][1].z, rb[i][1].w};
      half8 h, l;
#pragma unroll
      for (int j = 0; j < 8; ++j) {
        _Float16 hv = (_Float16)f[j];
        h[j] = hv;
        if (BSPL == 2) l[j] = (_Float16)(f[j] - (float)hv);
      }
      int off = row * BK + ((ci ^ ((row >> 1) & 3)) << 3);
      *(half8*)(&ldsB[b][0][0][0] + off) = h;
      if (BSPL == 2) *(half8*)(&ldsB[b][1][0][0] + off) = l;
    }
  };

  const int nk = K / BK;
  loadAB(0);
  stageLDS(0);
  if (nk > 1) loadAB(1);
  __syncthreads();

  for (int kt = 0; kt < nk; ++kt) {
    const int cur = kt & 1, nxt = cur ^ 1;
    if (kt + 1 < nk) stageLDS(nxt);
    if (kt + 2 < nk) loadAB(kt + 2);

    half8 af[FM][ASPL];
#pragma unroll
    for (int mi = 0; mi < FM; ++mi)
#pragma unroll
      for (int sa = 0; sa < ASPL; ++sa) {
        int row = wrow * WM + mi * 16 + l15;
        af[mi][sa] = *(const half8*)(&ldsA[cur][sa][0][0] + row * BK + ((g ^ ((row >> 1) & 3)) << 3));
      }
#pragma unroll
    for (int ni = 0; ni < FN; ++ni) {
      half8 bf[BSPL];
#pragma unroll
      for (int sb = 0; sb < BSPL; ++sb) {
        int row = wcol * WN + ni * 16 + l15;
        bf[sb] = *(const half8*)(&ldsB[cur][sb][0][0] + row * BK + ((g ^ ((row >> 1) & 3)) << 3));
      }
#pragma unroll
      for (int mi = 0; mi < FM; ++mi)
#pragma unroll
        for (int sa = 0; sa < ASPL; ++sa)
#pragma unroll
          for (int sb = 0; sb < BSPL; ++sb) {
            if (ASPL == 2 && BSPL == 2 && sa == 1 && sb == 1) continue;
            acc[mi][ni] = __builtin_amdgcn_mfma_f32_16x16x32_f16(af[mi][sa], bf[sb], acc[mi][ni], 0, 0, 0);
          }
    }
    __syncthreads();
  }

#pragma unroll
  for (int mi = 0; mi < FM; ++mi)
#pragma unroll
    for (int ni = 0; ni < FN; ++ni) {
      int col = bcol + wcol * WN + ni * 16 + l15;
      float bv = bias ? bias[col] : 0.f;
#pragma unroll
      for (int j = 0; j < 4; ++j) {
        int r = brow + wrow * WM + mi * 16 + g * 4 + j;
        float v = acc[mi][ni][j] * scale + bv;
        Cg[(size_t)r * ldc + col] = v;
        if constexpr (QF16) {
          if (col < 512) q16out[(size_t)r * 512 + col] = (_Float16)v;
        }
      }
    }
}

// ---------------------------------------------------------------- GEMM f16 x f16 (K3)
template<int BM,int BN,int THREADS,bool STATS,int MINW>
__global__ __launch_bounds__(THREADS, MINW) void gemm_ff16(
    const _Float16* __restrict__ Ag, int lda,
    const _Float16* __restrict__ Bg, int ldb,
    float* __restrict__ Cg, int ldc,
    int K, float scale,
    float* __restrict__ mxout, float* __restrict__ smout, int ntiles)
{
  constexpr int BK = 32;
  constexpr int WAVES_M = 2, WAVES_N = 2;
  constexpr int WM = BM / WAVES_M, WN = BN / WAVES_N;
  constexpr int FM = WM / 16, FN = WN / 16;
  constexpr int NCA = (BM * 4) / THREADS;
  constexpr int NCB = (BN * 4) / THREADS;

  __shared__ _Float16 ldsA[2][BM][BK];
  __shared__ _Float16 ldsB[2][BN][BK];

  const int tid  = threadIdx.x;
  const int lane = tid & 63;
  const int wid  = tid >> 6;
  const int wrow = wid >> 1, wcol = wid & 1;
  const int l15  = lane & 15, g = lane >> 4;
  const int brow = blockIdx.y * BM;
  const int bcol = blockIdx.x * BN;

  f32x4 acc[FM][FN];
#pragma unroll
  for (int mi = 0; mi < FM; ++mi)
#pragma unroll
    for (int ni = 0; ni < FN; ++ni)
      acc[mi][ni] = (f32x4){0.f, 0.f, 0.f, 0.f};

  half8 ra[NCA], rb[NCB];

  auto loadAB = [&](int kt) {
    const int k0 = kt * BK;
#pragma unroll
    for (int i = 0; i < NCA; ++i) {
      int c = tid + THREADS * i;
      int row = c >> 2, ci = c & 3;
      ra[i] = *(const half8*)(Ag + (size_t)(brow + row) * lda + k0 + ci * 8);
    }
#pragma unroll
    for (int i = 0; i < NCB; ++i) {
      int c = tid + THREADS * i;
      int row = c >> 2, ci = c & 3;
      rb[i] = *(const half8*)(Bg + (size_t)(bcol + row) * ldb + k0 + ci * 8);
    }
  };

  auto stageLDS = [&](int b) {
#pragma unroll
    for (int i = 0; i < NCA; ++i) {
      int c = tid + THREADS * i;
      int row = c >> 2, ci = c & 3;
      int off = row * BK + ((ci ^ ((row >> 1) & 3)) << 3);
      *(half8*)(&ldsA[b][0][0] + off) = ra[i];
    }
#pragma unroll
    for (int i = 0; i < NCB; ++i) {
      int c = tid + THREADS * i;
      int row = c >> 2, ci = c & 3;
      int off = row * BK + ((ci ^ ((row >> 1) & 3)) << 3);
      *(half8*)(&ldsB[b][0][0] + off) = rb[i];
    }
  };

  const int nk = K / BK;
  loadAB(0);
  stageLDS(0);
  if (nk > 1) loadAB(1);
  __syncthreads();

  for (int kt = 0; kt < nk; ++kt) {
    const int cur = kt & 1, nxt = cur ^ 1;
    if (kt + 1 < nk) stageLDS(nxt);
    if (kt + 2 < nk) loadAB(kt + 2);

    half8 af[FM];
#pragma unroll
    for (int mi = 0; mi < FM; ++mi) {
      int row = wrow * WM + mi * 16 + l15;
      af[mi] = *(const half8*)(&ldsA[cur][0][0] + row * BK + ((g ^ ((row >> 1) & 3)) << 3));
    }
#pragma unroll
    for (int ni = 0; ni < FN; ++ni) {
      int row = wcol * WN + ni * 16 + l15;
      half8 bf = *(const half8*)(&ldsB[cur][0][0] + row * BK + ((g ^ ((row >> 1) & 3)) << 3));
#pragma unroll
      for (int mi = 0; mi < FM; ++mi)
        acc[mi][ni] = __builtin_amdgcn_mfma_f32_16x16x32_f16(af[mi], bf, acc[mi][ni], 0, 0, 0);
    }
    __syncthreads();
  }

#pragma unroll
  for (int mi = 0; mi < FM; ++mi)
#pragma unroll
    for (int ni = 0; ni < FN; ++ni) {
      int col = bcol + wcol * WN + ni * 16 + l15;
#pragma unroll
      for (int j = 0; j < 4; ++j) {
        int r = brow + wrow * WM + mi * 16 + g * 4 + j;
        Cg[(size_t)r * ldc + col] = acc[mi][ni][j] * scale;
      }
    }

  if constexpr (STATS) {
    __shared__ float s_m2[BM][2];
    __shared__ float s_s2[BM][2];
#pragma unroll
    for (int mi = 0; mi < FM; ++mi)
#pragma unroll
      for (int j = 0; j < 4; ++j) {
        float v = -3.4e38f;
#pragma unroll
        for (int ni = 0; ni < FN; ++ni) v = fmaxf(v, acc[mi][ni][j] * scale);
        v = fmaxf(v, __shfl_xor(v, 1)); v = fmaxf(v, __shfl_xor(v, 2));
        v = fmaxf(v, __shfl_xor(v, 4)); v = fmaxf(v, __shfl_xor(v, 8));
        if (l15 == 0) s_m2[wrow * WM + mi * 16 + g * 4 + j][wcol] = v;
      }
    __syncthreads();
#pragma unroll
    for (int mi = 0; mi < FM; ++mi)
#pragma unroll
      for (int j = 0; j < 4; ++j) {
        int r = wrow * WM + mi * 16 + g * 4 + j;
        float mt = fmaxf(s_m2[r][0], s_m2[r][1]);
        float s = 0.f;
#pragma unroll
        for (int ni = 0; ni < FN; ++ni) s += __expf(acc[mi][ni][j] * scale - mt);
        s += __shfl_xor(s, 1); s += __shfl_xor(s, 2);
        s += __shfl_xor(s, 4); s += __shfl_xor(s, 8);
        if (l15 == 0) s_s2[r][wcol] = s;
      }
    __syncthreads();
    if (tid < BM) {
      float mt = fmaxf(s_m2[tid][0], s_m2[tid][1]);
      float st = s_s2[tid][0] + s_s2[tid][1];
      mxout[(size_t)(brow + tid) * ntiles + blockIdx.x] = mt;
      smout[(size_t)(brow + tid) * ntiles + blockIdx.x] = st;
    }
  }
}

// ---------------------------------------------------------------- reduce 4 planes -> f16
__global__ __launch_bounds__(256) void reduce4_f16(
    const float4* __restrict__ in, _Float16* __restrict__ out16, size_t plane4,
    const float4* __restrict__ csum4)
{
  size_t i = (size_t)blockIdx.x * 256 + threadIdx.x;
  float4 a = in[i], b = in[plane4 + i], c = in[2 * plane4 + i], d = in[3 * plane4 + i];
  float4 s = csum4[i & 127];
  half4 h;
  h[0] = (_Float16)(a.x + b.x + c.x + d.x - s.x);
  h[1] = (_Float16)(a.y + b.y + c.y + d.y - s.y);
  h[2] = (_Float16)(a.z + b.z + c.z + d.z - s.z);
  h[3] = (_Float16)(a.w + b.w + c.w + d.w - s.w);
  *(half4*)(out16 + i * 4) = h;
}

// ---------------------------------------------------------------- stats combine
__global__ __launch_bounds__(256) void softmax_combine(
    const float* __restrict__ mx, const float* __restrict__ sm,
    float* __restrict__ rowm, float* __restrict__ rowinv)
{
  const int row = blockIdx.x * 4 + (threadIdx.x >> 6);
  const int lane = threadIdx.x & 63;
  float mt = mx[(size_t)row * 64 + lane];
  float m = mt;
#pragma unroll
  for (int off = 32; off; off >>= 1) m = fmaxf(m, __shfl_xor(m, off));
  float s = sm[(size_t)row * 64 + lane] * __expf(mt - m);
#pragma unroll
  for (int off = 32; off; off >>= 1) s += __shfl_xor(s, off);
  if (lane == 0) { rowm[row] = m; rowinv[row] = 1.0f / s; }
}

// ---------------------------------------------------------------- fused attn-write + PV
// Round-5 structure verbatim (verified 205us): 1 barrier/step, dbuf LDS,
// A-staging 32B/thread over tid<256, B via LDS. Changes: setprio around MFMA
// cluster; vals partials stored f16.
__global__ __launch_bounds__(512, 4) void pv_fused(
    float* __restrict__ attn,            // [8192][8192] logits in, attention out
    const _Float16* __restrict__ vT16,   // [512][8192] f16
    const float* __restrict__ rowm, const float* __restrict__ rowinv,
    _Float16* __restrict__ vals16)       // [4][8192][512] f16
{
  constexpr int BM = 64, BN = 512, BK = 32, NSTEP = 64;  // KC = 2048
  __shared__ _Float16 ldsA[2][BM][BK];   // 8 KB
  __shared__ _Float16 ldsB[2][BN][BK];   // 64 KB
  __shared__ float s_m[BM], s_inv[BM];

  const int tid = threadIdx.x, lane = tid & 63, wid = tid >> 6;
  const int wrow = wid >> 2, wcol = wid & 3;   // 2 x 4 waves
  const int l15 = lane & 15, g = lane >> 4;
  const int kc = blockIdx.x, brow = blockIdx.y * BM;
  const size_t kbase = (size_t)kc * 2048;

  if (tid < BM) { s_m[tid] = rowm[brow + tid]; s_inv[tid] = rowinv[brow + tid]; }

  f32x4 acc[2][8];
#pragma unroll
  for (int mi = 0; mi < 2; ++mi)
#pragma unroll
    for (int ni = 0; ni < 8; ++ni) acc[mi][ni] = (f32x4){0.f, 0.f, 0.f, 0.f};

  const int arow = (tid & 255) >> 2, aci = tid & 3;
  float4 ra[2];
  half8 rbh[4];

  auto loadA = [&](int kt) {
    if (tid < 256) {
      const float4* p = (const float4*)(attn + (size_t)(brow + arow) * 8192 + kbase + kt * BK + aci * 8);
      ra[0] = p[0]; ra[1] = p[1];
    }
  };
  auto loadB = [&](int kt) {
#pragma unroll
    for (int i = 0; i < 4; ++i) {
      int c = tid + 512 * i; int r = c >> 2, ci = c & 3;
      rbh[i] = *(const half8*)(vT16 + (size_t)r * 8192 + kbase + kt * BK + ci * 8);
    }
  };
  auto stage = [&](int kt, int b) {
    if (tid < 256) {
      const float m = s_m[arow], inv = s_inv[arow];
      float f[8] = {ra[0].x, ra[0].y, ra[0].z, ra[0].w, ra[1].x, ra[1].y, ra[1].z, ra[1].w};
      float e[8]; half8 h;
#pragma unroll
      for (int j = 0; j < 8; ++j) {
        e[j] = __expf(f[j] - m) * inv;
        h[j] = (_Float16)e[j];
      }
      float4* w = (float4*)(attn + (size_t)(brow + arow) * 8192 + kbase + kt * BK + aci * 8);
      w[0] = make_float4(e[0], e[1], e[2], e[3]);
      w[1] = make_float4(e[4], e[5], e[6], e[7]);
      int off = arow * BK + ((aci ^ ((arow >> 1) & 3)) << 3);
      *(half8*)(&ldsA[b][0][0] + off) = h;
    }
#pragma unroll
    for (int i = 0; i < 4; ++i) {
      int c = tid + 512 * i; int r = c >> 2, ci = c & 3;
      int off2 = r * BK + ((ci ^ ((r >> 1) & 3)) << 3);
      *(half8*)(&ldsB[b][0][0] + off2) = rbh[i];
    }
  };

  loadA(0); loadB(0);
  __syncthreads();            // s_m / s_inv visible
  stage(0, 0);
  loadA(1); loadB(1);
  __syncthreads();            // buf0 staged

  for (int kt = 0; kt < NSTEP; ++kt) {
    const int cur = kt & 1, nxt = cur ^ 1;
    if (kt + 1 < NSTEP) stage(kt + 1, nxt);
    if (kt + 2 < NSTEP) { loadA(kt + 2); loadB(kt + 2); }
    half8 af[2];
#pragma unroll
    for (int mi = 0; mi < 2; ++mi) {
      int row = wrow * 32 + mi * 16 + l15;
      af[mi] = *(const half8*)(&ldsA[cur][0][0] + row * BK + ((g ^ ((row >> 1) & 3)) << 3));
    }
    __builtin_amdgcn_s_setprio(1);
#pragma unroll
    for (int ni = 0; ni < 8; ++ni) {
      int rn = wcol * 128 + ni * 16 + l15;
      half8 bf = *(const half8*)(&ldsB[cur][0][0] + rn * BK + ((g ^ ((rn >> 1) & 3)) << 3));
#pragma unroll
      for (int mi = 0; mi < 2; ++mi)
        acc[mi][ni] = __builtin_amdgcn_mfma_f32_16x16x32_f16(af[mi], bf, acc[mi][ni], 0, 0, 0);
    }
    __builtin_amdgcn_s_setprio(0);
    __syncthreads();
  }

  const size_t plane = (size_t)8192 * 512;
#pragma unroll
  for (int mi = 0; mi < 2; ++mi)
#pragma unroll
    for (int ni = 0; ni < 8; ++ni) {
      int col = wcol * 128 + ni * 16 + l15;
#pragma unroll
      for (int j = 0; j < 4; ++j) {
        int row = brow + wrow * 32 + mi * 16 + g * 4 + j;
        vals16[(size_t)kc * plane + (size_t)row * 512 + col] = (_Float16)acc[mi][ni][j];
      }
    }
}

// ---------------------------------------------------------------- launch
extern "C" void kernel_launch(void* const* d_in, const int* in_sizes, int n_in,
                              void* d_out, int out_size, void* d_ws, size_t ws_size,
                              hipStream_t stream)
{
  const float* x    = (const float*)d_in[0];
  const float* Amat = (const float*)d_in[1];
  const float* Wqkv = (const float*)d_in[2];
  const float* bqkv = (const float*)d_in[3];
  const float* Wo   = (const float*)d_in[4];
  const float* bo   = (const float*)d_in[5];

  float* o    = (float*)d_out;                       // [8192,512]
  float* attn = (float*)d_out + (size_t)8192 * 512;  // [8192,8192]

  float* ws = (float*)d_ws;
  _Float16*  vals16 = (_Float16*)ws;              // 16,777,216 f16 (4 planes, 8.4M float-slots)
  float*     qkv    = ws;                         // 12,582,912 (dead after k0T/vT/q16)
  float*     k0T    = ws + 12582912;              //  4,194,304 (dead after K2/halfcolsum)
  _Float16*  vT16   = (_Float16*)(ws + 16777216); //  2,097,152 float-slots
  float*     WqkvT  = ws + 18874368;              //    786,432
  float*     WoT    = ws + 19660800;              //    262,144
  _Float16*  kbuf16 = (_Float16*)(ws + 19922944); //  2,097,152 float-slots (f16 [8192][512])
  float*     mx     = ws + 24117248;              //    524,288
  float*     sm     = ws + 24641536;              //    524,288
  float*     rowm   = ws + 25165824;              //      8,192
  float*     rowinv = ws + 25174016;              //      8,192
  float*     csum   = ws + 25182208;              //        512 (pad to 1024)
  _Float16*  q16    = (_Float16*)(ws + 25183232); //  2,097,152 float-slots (f16 [8192][512])
  float*     kpart  = attn;                       // d_out attn region pre-K3

  const dim3 b256(256), b512(512);
  const float qk_scale = 0.04419417382415922f;  // 1/sqrt(512)
  const size_t plane = (size_t)8192 * 512;

  transpose_f32<<<dim3(48, 16), b256, 0, stream>>>(Wqkv, 1536, WqkvT, 512);
  transpose_f32<<<dim3(16, 16), b256, 0, stream>>>(Wo, 512, WoT, 512);

  // K1: qkv = x @ Wqkv + bqkv (3-pass) + fused f16 copy of q-third
  gemm_bt<2, 2, 128, 128, 2, 2, 256, 1, false, true, 2, 0>
      <<<dim3(12, 64), b256, 0, stream>>>(
      x, 512, 0, WqkvT, 512, qkv, 1536, 0, bqkv, 512, 1.0f, q16);

  transpose_f32<<<dim3(16, 256), b256, 0, stream>>>(qkv + 512, 1536, k0T, 8192);
  transpose_f32_f16<<<dim3(16, 256), b256, 0, stream>>>(qkv + 1024, 1536, vT16, 8192);
  halfcolsum<<<dim3(512), b256, 0, stream>>>(k0T, csum);

  // K2: k = A @ k0, split-K into 4 chunks, partials in d_out scratch
  gemm_bt<1, 2, 128, 256, 2, 4, 512, 1, true, false, 4, 0>
      <<<dim3(2, 64, 4), b512, 0, stream>>>(
      Amat, 8192, 0, k0T, 8192, kpart, 512, plane, nullptr, 2048, 1.0f, nullptr);

  // kbuf16 = f16(sum of partials - 0.5*colsum(k0))
  reduce4_f16<<<dim3(4096), b256, 0, stream>>>((const float4*)kpart, kbuf16, plane / 4,
                                               (const float4*)csum);

  // K3: logits = (q16 @ kbuf16^T)*scale + per-tile softmax stats
  gemm_ff16<128, 128, 256, true, 4>
      <<<dim3(64, 64), b256, 0, stream>>>(
      q16, 512, kbuf16, 512, attn, 8192, 512, qk_scale, mx, sm, 64);

  softmax_combine<<<dim3(2048), b256, 0, stream>>>(mx, sm, rowm, rowinv);

  // K5': attention = exp(l-m)/s in place; vals partials f16
  pv_fused<<<dim3(4, 128), b512, 0, stream>>>(attn, vT16, rowm, rowinv, vals16);

  // K6: o = (sum of 4 f16 vals partials) @ Wo + bo
  gemm_bt<1, 1, 128, 128, 2, 2, 256, 4, false, false, 3, 1>
      <<<dim3(4, 64), b256, 0, stream>>>(
      vals16, 512, plane, WoT, 512, o, 512, 0, bo, 512, 1.0f, nullptr);
}